// Round 1
// baseline (435.762 us; speedup 1.0000x reference)
//
#include <hip/hip_runtime.h>
#include <hip/hip_bf16.h>
#include <cstdint>

typedef __bf16 bf16x8 __attribute__((ext_vector_type(8)));
typedef float  f32x4  __attribute__((ext_vector_type(4)));

struct alignas(4) us2 { unsigned short x, y; };
struct alignas(8) us4 { unsigned short x, y, z, w; };

__device__ __forceinline__ unsigned short f2bf(float f) {
    union { float f; unsigned u; } a; a.f = f;
    unsigned r = a.u + 0x7fffu + ((a.u >> 16) & 1u);   // round-to-nearest-even
    return (unsigned short)(r >> 16);
}

__device__ __forceinline__ void gl_lds16(const void* g, void* s) {
    __builtin_amdgcn_global_load_lds(
        (const __attribute__((address_space(1))) void*)g,
        (__attribute__((address_space(3))) void*)s, 16, 0, 0);
}

// C = A(MxK) @ W(NxK)^T ; A,W bf16 (as ushort), fp32 accumulate.
// EPI 0: outb = bf16(gelu_exact(acc + bias[col]))
// EPI 1: outf = acc + bias[col]  (fp32)
template<int EPI>
__global__ __launch_bounds__(256)
void gemm_bt(const unsigned short* __restrict__ A,
             const unsigned short* __restrict__ W,
             const float* __restrict__ bias,
             unsigned short* __restrict__ outb,
             float* __restrict__ outf,
             int M, int N, int K)
{
    __shared__ unsigned short sA[128 * 64];
    __shared__ unsigned short sB[128 * 64];

    const int tid  = threadIdx.x;
    const int lane = tid & 63;
    const int wv   = tid >> 6;          // 0..3
    const int wr   = wv >> 1, wc = wv & 1;
    const size_t row0 = (size_t)blockIdx.y * 128;
    const size_t col0 = (size_t)blockIdx.x * 128;

    f32x4 acc[4][4] = {};

    // staging: thread t loads 16B: tile row = t>>3 (+32 per chunk), col = (t&7)*8
    const int srow = tid >> 3;
    const int scol = (tid & 7) * 8;

    for (int k0 = 0; k0 < K; k0 += 64) {
#pragma unroll
        for (int c = 0; c < 4; ++c) {
            gl_lds16(A + (row0 + c * 32 + srow) * K + k0 + scol,
                     sA + (c * 32 + srow) * 64 + scol);
            gl_lds16(W + (col0 + c * 32 + srow) * K + k0 + scol,
                     sB + (c * 32 + srow) * 64 + scol);
        }
        __syncthreads();   // compiler emits vmcnt(0) drain before s_barrier

        {
            const int lr = lane & 15;
            const int lk = (lane >> 4) * 8;
#pragma unroll
            for (int kk = 0; kk < 64; kk += 32) {
                bf16x8 aF[4], bF[4];
#pragma unroll
                for (int mi = 0; mi < 4; ++mi)
                    aF[mi] = *(const bf16x8*)&sA[(wr * 64 + mi * 16 + lr) * 64 + kk + lk];
#pragma unroll
                for (int ni = 0; ni < 4; ++ni)
                    bF[ni] = *(const bf16x8*)&sB[(wc * 64 + ni * 16 + lr) * 64 + kk + lk];
#pragma unroll
                for (int mi = 0; mi < 4; ++mi)
#pragma unroll
                    for (int ni = 0; ni < 4; ++ni)
                        acc[mi][ni] = __builtin_amdgcn_mfma_f32_16x16x32_bf16(
                            aF[mi], bF[ni], acc[mi][ni], 0, 0, 0);
            }
        }
        __syncthreads();
    }

    // epilogue: D layout col = lane&15, row = (lane>>4)*4 + reg   [m89]
    const int lr = lane & 15, lq = lane >> 4;
#pragma unroll
    for (int ni = 0; ni < 4; ++ni) {
        const size_t col = col0 + wc * 64 + ni * 16 + lr;
        const float bv = bias[col];
#pragma unroll
        for (int mi = 0; mi < 4; ++mi) {
#pragma unroll
            for (int r = 0; r < 4; ++r) {
                const size_t row = row0 + wr * 64 + mi * 16 + lq * 4 + r;
                float v = acc[mi][ni][r] + bv;
                if (EPI == 0) {
                    float g = 0.5f * v * (1.0f + erff(v * 0.70710678118654752f));
                    outb[row * N + col] = f2bf(g);
                } else {
                    outf[row * N + col] = v;
                }
            }
        }
    }
}

__global__ void cvt_bf16(const float* __restrict__ in, unsigned short* __restrict__ out, int n4) {
    const int stride = gridDim.x * blockDim.x;
    for (int i = blockIdx.x * blockDim.x + threadIdx.x; i < n4; i += stride) {
        float4 v = ((const float4*)in)[i];
        us4 o{ f2bf(v.x), f2bf(v.y), f2bf(v.z), f2bf(v.w) };
        ((us4*)out)[i] = o;
    }
}

// zm[row][i] = bf16(z[row][2i]) : float4 covers z[4i..4i+3] -> evens 2i,2i+1
__global__ void pack_even(const float* __restrict__ z, unsigned short* __restrict__ zm, int n4) {
    const int stride = gridDim.x * blockDim.x;
    for (int i = blockIdx.x * blockDim.x + threadIdx.x; i < n4; i += stride) {
        float4 v = ((const float4*)z)[i];
        us2 o{ f2bf(v.x), f2bf(v.z) };
        ((us2*)zm)[i] = o;
    }
}

// out currently holds s_t (fp32, row-major 16384x1024). In-place:
// z_out[:,2i] = z[:,2i]; z_out[:,2i+1] = z[:,2i+1]*exp(s[i]) + t[i]; log_det += sum(s)
__global__ __launch_bounds__(256)
void finalize(const float* __restrict__ z, const float* __restrict__ ld_in,
              float* __restrict__ out, float* __restrict__ ldout)
{
    __shared__ float srow[1024];
    __shared__ float red[4];
    const int row = blockIdx.x;
    float* orow = out + (size_t)row * 1024;
    const float* zr = z + (size_t)row * 1024;

    ((float4*)srow)[threadIdx.x] = ((const float4*)orow)[threadIdx.x];
    __syncthreads();

    float lsum = 0.f;
#pragma unroll
    for (int i = threadIdx.x; i < 512; i += 256) {
        float sv = srow[i], tv = srow[512 + i];
        float2 zp = ((const float2*)zr)[i];
        float2 o;
        o.x = zp.x;
        o.y = zp.y * expf(sv) + tv;
        ((float2*)orow)[i] = o;
        lsum += sv;
    }
#pragma unroll
    for (int off = 32; off > 0; off >>= 1) lsum += __shfl_down(lsum, off, 64);
    if ((threadIdx.x & 63) == 0) red[threadIdx.x >> 6] = lsum;
    __syncthreads();
    if (threadIdx.x == 0) ldout[row] = ld_in[row] + red[0] + red[1] + red[2] + red[3];
}

extern "C" void kernel_launch(void* const* d_in, const int* in_sizes, int n_in,
                              void* d_out, int out_size, void* d_ws, size_t ws_size,
                              hipStream_t stream)
{
    const float* z  = (const float*)d_in[0];
    const float* ld = (const float*)d_in[1];
    const float* W1 = (const float*)d_in[2];
    const float* b1 = (const float*)d_in[3];
    const float* W2 = (const float*)d_in[4];
    const float* b2 = (const float*)d_in[5];
    const float* W3 = (const float*)d_in[6];
    const float* b3 = (const float*)d_in[7];

    float* out   = (float*)d_out;
    float* zout  = out;
    float* ldout = out + (size_t)16384 * 1024;

    char* w = (char*)d_ws;
    unsigned short* zm  = (unsigned short*)w; w += (size_t)16384 * 512 * 2;
    unsigned short* w1b = (unsigned short*)w; w += (size_t)2048 * 512 * 2;
    unsigned short* w2b = (unsigned short*)w; w += (size_t)2048 * 2048 * 2;
    unsigned short* w3b = (unsigned short*)w; w += (size_t)1024 * 2048 * 2;
    unsigned short* h1  = (unsigned short*)w; w += (size_t)16384 * 2048 * 2;
    unsigned short* h2  = (unsigned short*)w; w += (size_t)16384 * 2048 * 2;

    cvt_bf16 <<<512,  256, 0, stream>>>(W1, w1b, 2048 * 512 / 4);
    cvt_bf16 <<<2048, 256, 0, stream>>>(W2, w2b, 2048 * 2048 / 4);
    cvt_bf16 <<<1024, 256, 0, stream>>>(W3, w3b, 1024 * 2048 / 4);
    pack_even<<<2048, 256, 0, stream>>>(z, zm, 16384 * 1024 / 4);

    gemm_bt<0><<<dim3(16, 128), 256, 0, stream>>>(zm, w1b, b1, h1, nullptr, 16384, 2048, 512);
    gemm_bt<0><<<dim3(16, 128), 256, 0, stream>>>(h1, w2b, b2, h2, nullptr, 16384, 2048, 2048);
    gemm_bt<1><<<dim3(8, 128),  256, 0, stream>>>(h2, w3b, b3, nullptr, zout, 16384, 1024, 2048);

    finalize<<<16384, 256, 0, stream>>>(z, ld, zout, ldout);
}

// Round 2
// 418.906 us; speedup vs baseline: 1.0402x; 1.0402x over previous
//
#include <hip/hip_runtime.h>
#include <hip/hip_bf16.h>
#include <cstdint>

typedef __bf16 bf16x8 __attribute__((ext_vector_type(8)));
typedef float  f32x4  __attribute__((ext_vector_type(4)));

struct alignas(4) us2 { unsigned short x, y; };
struct alignas(8) us4 { unsigned short x, y, z, w; };

__device__ __forceinline__ unsigned short f2bf(float f) {
    union { float f; unsigned u; } a; a.f = f;
    unsigned r = a.u + 0x7fffu + ((a.u >> 16) & 1u);   // round-to-nearest-even
    return (unsigned short)(r >> 16);
}

__device__ __forceinline__ void gl_lds16(const void* g, void* s) {
    __builtin_amdgcn_global_load_lds(
        (const __attribute__((address_space(1))) void*)g,
        (__attribute__((address_space(3))) void*)s, 16, 0, 0);
}

#define SBAR()    do { __builtin_amdgcn_sched_barrier(0); __builtin_amdgcn_s_barrier(); __builtin_amdgcn_sched_barrier(0); } while (0)
#define WAITLG0() do { asm volatile("s_waitcnt lgkmcnt(0)" ::: "memory"); __builtin_amdgcn_sched_barrier(0); } while (0)
#define WAITVM(N) do { asm volatile("s_waitcnt vmcnt(" #N ")" ::: "memory"); __builtin_amdgcn_sched_barrier(0); } while (0)

// C = A(MxK) @ W(NxK)^T, bf16 in, fp32 acc. 256x256 tile, BK=32, 8 waves (2Mx4N),
// quad-buffered LDS (4 slots x (16KB A + 16KB B) = 128KB), stage k+3 while computing k,
// counted vmcnt(8) certification (never drain in main loop). Chunk-XOR LDS swizzle
// (linear gload_lds dest + pre-swizzled global source + swizzled ds_read).
// EPI 0: outb = bf16(gelu_exact(acc + bias[col])) ; EPI 1: outf = acc + bias[col].
template<int EPI, int K, int N>
__global__ __launch_bounds__(512, 2)
void gemm256(const unsigned short* __restrict__ A,
             const unsigned short* __restrict__ W,
             const float* __restrict__ bias,
             unsigned short* __restrict__ outb,
             float* __restrict__ outf)
{
    extern __shared__ char smem[];
    constexpr int NT = K / 32;
    constexpr int GX = N / 256;

    const int tid  = threadIdx.x;
    const int lane = tid & 63;
    const int wv   = tid >> 6;           // 0..7
    const int wr   = wv >> 2, wc = wv & 3;

    // T1: bijective XCD swizzle (nwg divisible by 8 for all our shapes)
    const int bid = blockIdx.y * GX + blockIdx.x;
    const int nwg = GX * (int)gridDim.y;
    const int swz = (bid & 7) * (nwg >> 3) + (bid >> 3);
    const size_t row0 = (size_t)(swz / GX) * 256;
    const size_t col0 = (size_t)(swz % GX) * 256;

    char* sA = smem;            // 4 slots x 16KB
    char* sB = smem + 65536;    // 4 slots x 16KB

    // ---- staging precompute (thread stages 2 A-chunks + 2 B-chunks per K-tile) ----
    // LDS chunk q (16B) holds source (r = q>>2, c = (q&3) ^ (r&3)); dest is lane-linear.
    const int r1  = tid >> 2;                               // 0..127
    const int cse = (((tid & 3) ^ (r1 & 3)) << 3);          // source element offset 0/8/16/24
    const unsigned short* ag0 = A + (row0 + r1      ) * (size_t)K + cse;
    const unsigned short* ag1 = A + (row0 + r1 + 128) * (size_t)K + cse;
    const unsigned short* bg0 = W + (col0 + r1      ) * (size_t)K + cse;
    const unsigned short* bg1 = W + (col0 + r1 + 128) * (size_t)K + cse;
    const int dst0 = tid * 16;
    const int dst1 = tid * 16 + 8192;

    auto stage = [&](int h, int s, int kt) {
        if (h == 0) {
            gl_lds16(ag0 + (size_t)kt * 32, sA + s * 16384 + dst0);
            gl_lds16(bg0 + (size_t)kt * 32, sB + s * 16384 + dst0);
        } else {
            gl_lds16(ag1 + (size_t)kt * 32, sA + s * 16384 + dst1);
            gl_lds16(bg1 + (size_t)kt * 32, sB + s * 16384 + dst1);
        }
    };

    // ---- fragment-read precompute: swizzle folds to a lane-only 16B-slot XOR ----
    const int ln15 = lane & 15;
    const int xoff = (((lane >> 4) ^ (lane & 3)) << 4);     // bytes
    const int arow = wr * 128 + ln15;                       // + mi*16
    const int brow = wc * 64  + ln15;                       // + nf*16

    f32x4 acc[8][4] = {};

    // ---- prologue: stage tiles 0,1,2 into slots 0,1,2 ----
#pragma unroll
    for (int kt = 0; kt < 3; ++kt) {
        stage(0, kt, kt);
        stage(1, kt, kt);
    }
    WAITVM(8);      // tile 0 landed (tiles 1,2 still in flight)
    SBAR();

    for (int k = 0; k < NT; ++k) {
        const int slot = k & 3;
        const char* cA = sA + slot * 16384;
        const char* cB = sB + slot * 16384;
        bf16x8 aF[8], bF[2];

        // ================= phase A (N-half 0) =================
#pragma unroll
        for (int mi = 0; mi < 8; ++mi)
            aF[mi] = *(const bf16x8*)(cA + (arow + mi * 16) * 64 + xoff);
        bF[0] = *(const bf16x8*)(cB + (brow +  0) * 64 + xoff);
        bF[1] = *(const bf16x8*)(cB + (brow + 16) * 64 + xoff);
        if (k < NT - 3) stage(0, (k + 3) & 3, k + 3);
        SBAR();
        WAITLG0();
        __builtin_amdgcn_s_setprio(1);
#pragma unroll
        for (int mi = 0; mi < 8; ++mi) {
            acc[mi][0] = __builtin_amdgcn_mfma_f32_16x16x32_bf16(aF[mi], bF[0], acc[mi][0], 0, 0, 0);
            acc[mi][1] = __builtin_amdgcn_mfma_f32_16x16x32_bf16(aF[mi], bF[1], acc[mi][1], 0, 0, 0);
        }
        __builtin_amdgcn_s_setprio(0);
        SBAR();

        // ================= phase B (N-half 1) =================
        bF[0] = *(const bf16x8*)(cB + (brow + 32) * 64 + xoff);
        bF[1] = *(const bf16x8*)(cB + (brow + 48) * 64 + xoff);
        if (k < NT - 3) stage(1, (k + 3) & 3, k + 3);
        // certify tile k+1 (counted: keep stages of k+2,k+3 in flight)
        if (k < NT - 3)      WAITVM(8);
        else if (k == NT - 3) WAITVM(4);
        else if (k == NT - 2) WAITVM(0);
        SBAR();
        WAITLG0();
        __builtin_amdgcn_s_setprio(1);
#pragma unroll
        for (int mi = 0; mi < 8; ++mi) {
            acc[mi][2] = __builtin_amdgcn_mfma_f32_16x16x32_bf16(aF[mi], bF[0], acc[mi][2], 0, 0, 0);
            acc[mi][3] = __builtin_amdgcn_mfma_f32_16x16x32_bf16(aF[mi], bF[1], acc[mi][3], 0, 0, 0);
        }
        __builtin_amdgcn_s_setprio(0);
        SBAR();
    }

    // ---- epilogue: D layout col = lane&15, row = (lane>>4)*4 + reg ----
    const int lq = lane >> 4;
#pragma unroll
    for (int nf = 0; nf < 4; ++nf) {
        const size_t col = col0 + wc * 64 + nf * 16 + ln15;
        const float bv = bias[col];
#pragma unroll
        for (int mi = 0; mi < 8; ++mi) {
#pragma unroll
            for (int r = 0; r < 4; ++r) {
                const size_t row = row0 + wr * 128 + mi * 16 + lq * 4 + r;
                float v = acc[mi][nf][r] + bv;
                if (EPI == 0) {
                    float g = 0.5f * v * (1.0f + erff(v * 0.70710678118654752f));
                    outb[row * N + col] = f2bf(g);
                } else {
                    outf[row * N + col] = v;
                }
            }
        }
    }
}

__global__ void cvt_bf16(const float* __restrict__ in, unsigned short* __restrict__ out, int n4) {
    const int stride = gridDim.x * blockDim.x;
    for (int i = blockIdx.x * blockDim.x + threadIdx.x; i < n4; i += stride) {
        float4 v = ((const float4*)in)[i];
        us4 o{ f2bf(v.x), f2bf(v.y), f2bf(v.z), f2bf(v.w) };
        ((us4*)out)[i] = o;
    }
}

// zm[row][i] = bf16(z[row][2i])
__global__ void pack_even(const float* __restrict__ z, unsigned short* __restrict__ zm, int n4) {
    const int stride = gridDim.x * blockDim.x;
    for (int i = blockIdx.x * blockDim.x + threadIdx.x; i < n4; i += stride) {
        float4 v = ((const float4*)z)[i];
        us2 o{ f2bf(v.x), f2bf(v.z) };
        ((us2*)zm)[i] = o;
    }
}

// out currently holds s_t (fp32, 16384x1024). In place:
// z_out[:,2i]=z[:,2i]; z_out[:,2i+1]=z[:,2i+1]*exp(s[i])+t[i]; log_det += sum(s)
__global__ __launch_bounds__(256)
void finalize(const float* __restrict__ z, const float* __restrict__ ld_in,
              float* __restrict__ out, float* __restrict__ ldout)
{
    __shared__ float srow[1024];
    __shared__ float red[4];
    const int row = blockIdx.x;
    float* orow = out + (size_t)row * 1024;
    const float* zr = z + (size_t)row * 1024;

    ((float4*)srow)[threadIdx.x] = ((const float4*)orow)[threadIdx.x];
    __syncthreads();

    float lsum = 0.f;
#pragma unroll
    for (int i = threadIdx.x; i < 512; i += 256) {
        float sv = srow[i], tv = srow[512 + i];
        float2 zp = ((const float2*)zr)[i];
        float2 o;
        o.x = zp.x;
        o.y = zp.y * expf(sv) + tv;
        ((float2*)orow)[i] = o;
        lsum += sv;
    }
#pragma unroll
    for (int off = 32; off > 0; off >>= 1) lsum += __shfl_down(lsum, off, 64);
    if ((threadIdx.x & 63) == 0) red[threadIdx.x >> 6] = lsum;
    __syncthreads();
    if (threadIdx.x == 0) ldout[row] = ld_in[row] + red[0] + red[1] + red[2] + red[3];
}

extern "C" void kernel_launch(void* const* d_in, const int* in_sizes, int n_in,
                              void* d_out, int out_size, void* d_ws, size_t ws_size,
                              hipStream_t stream)
{
    const float* z  = (const float*)d_in[0];
    const float* ld = (const float*)d_in[1];
    const float* W1 = (const float*)d_in[2];
    const float* b1 = (const float*)d_in[3];
    const float* W2 = (const float*)d_in[4];
    const float* b2 = (const float*)d_in[5];
    const float* W3 = (const float*)d_in[6];
    const float* b3 = (const float*)d_in[7];

    float* out   = (float*)d_out;
    float* zout  = out;
    float* ldout = out + (size_t)16384 * 1024;

    char* w = (char*)d_ws;
    unsigned short* zm  = (unsigned short*)w; w += (size_t)16384 * 512 * 2;
    unsigned short* w1b = (unsigned short*)w; w += (size_t)2048 * 512 * 2;
    unsigned short* w2b = (unsigned short*)w; w += (size_t)2048 * 2048 * 2;
    unsigned short* w3b = (unsigned short*)w; w += (size_t)1024 * 2048 * 2;
    unsigned short* h1  = (unsigned short*)w; w += (size_t)16384 * 2048 * 2;
    unsigned short* h2  = (unsigned short*)w; w += (size_t)16384 * 2048 * 2;

    // allow 128KB dynamic LDS (idempotent; errors ignored)
    (void)hipFuncSetAttribute((const void*)&gemm256<0, 512,  2048>,
                              hipFuncAttributeMaxDynamicSharedMemorySize, 131072);
    (void)hipFuncSetAttribute((const void*)&gemm256<0, 2048, 2048>,
                              hipFuncAttributeMaxDynamicSharedMemorySize, 131072);
    (void)hipFuncSetAttribute((const void*)&gemm256<1, 2048, 1024>,
                              hipFuncAttributeMaxDynamicSharedMemorySize, 131072);

    cvt_bf16 <<<512,  256, 0, stream>>>(W1, w1b, 2048 * 512 / 4);
    cvt_bf16 <<<2048, 256, 0, stream>>>(W2, w2b, 2048 * 2048 / 4);
    cvt_bf16 <<<1024, 256, 0, stream>>>(W3, w3b, 1024 * 2048 / 4);
    pack_even<<<2048, 256, 0, stream>>>(z, zm, 16384 * 1024 / 4);

    gemm256<0, 512,  2048><<<dim3(8, 64), 512, 131072, stream>>>(zm, w1b, b1, h1, nullptr);
    gemm256<0, 2048, 2048><<<dim3(8, 64), 512, 131072, stream>>>(h1, w2b, b2, h2, nullptr);
    gemm256<1, 2048, 1024><<<dim3(4, 64), 512, 131072, stream>>>(h2, w3b, b3, nullptr, zout);

    finalize<<<16384, 256, 0, stream>>>(z, ld, zout, ldout);
}

// Round 3
// 389.179 us; speedup vs baseline: 1.1197x; 1.0764x over previous
//
#include <hip/hip_runtime.h>
#include <hip/hip_bf16.h>
#include <cstdint>

typedef __bf16 bf16x8 __attribute__((ext_vector_type(8)));
typedef float  f32x4  __attribute__((ext_vector_type(4)));

struct alignas(4) us2 { unsigned short x, y; };
struct alignas(8) us4 { unsigned short x, y, z, w; };

__device__ __forceinline__ unsigned short f2bf(float f) {
    union { float f; unsigned u; } a; a.f = f;
    unsigned r = a.u + 0x7fffu + ((a.u >> 16) & 1u);   // round-to-nearest-even
    return (unsigned short)(r >> 16);
}

__device__ __forceinline__ void gl_lds16(const void* g, void* s) {
    __builtin_amdgcn_global_load_lds(
        (const __attribute__((address_space(1))) void*)g,
        (__attribute__((address_space(3))) void*)s, 16, 0, 0);
}

#define SBAR()    do { __builtin_amdgcn_sched_barrier(0); __builtin_amdgcn_s_barrier(); __builtin_amdgcn_sched_barrier(0); } while (0)
#define WAITLG0() do { asm volatile("s_waitcnt lgkmcnt(0)" ::: "memory"); __builtin_amdgcn_sched_barrier(0); } while (0)
#define WAITVM(N) do { asm volatile("s_waitcnt vmcnt(" #N ")" ::: "memory"); __builtin_amdgcn_sched_barrier(0); } while (0)

// C = A(MxK) @ W(NxK)^T, bf16 in, fp32 acc. 256x256 tile, BK=32, 8 waves (2Mx4N),
// quad-buffered LDS, stage k+3 while computing k, counted vmcnt(8).
// LDS swizzle v2: chunk-col ^= (row>>1)&3  -> quarter-wave bank-balanced ds_read_b128.
// EPI 0: outb = bf16(gelu_exact(acc+bias)) ; EPI 1: outf = acc+bias ;
// EPI 2: fused coupling (W interleaved s/t): even col c=2j -> s_j, odd -> t_j.
template<int EPI, int K, int N>
__global__ __launch_bounds__(512, 2)
void gemm256(const unsigned short* __restrict__ A,
             const unsigned short* __restrict__ W,
             const float* __restrict__ bias,
             unsigned short* __restrict__ outb,
             float* __restrict__ outf,
             const float* __restrict__ zin,
             float* __restrict__ ldout)
{
    extern __shared__ char smem[];
    constexpr int NT = K / 32;
    constexpr int GX = N / 256;

    const int tid  = threadIdx.x;
    const int lane = tid & 63;
    const int wv   = tid >> 6;           // 0..7
    const int wr   = wv >> 2, wc = wv & 3;

    // T1: bijective XCD swizzle (nwg divisible by 8 for all our shapes)
    const int bid = blockIdx.y * GX + blockIdx.x;
    const int nwg = GX * (int)gridDim.y;
    const int swz = (bid & 7) * (nwg >> 3) + (bid >> 3);
    const size_t row0 = (size_t)(swz / GX) * 256;
    const size_t col0 = (size_t)(swz % GX) * 256;

    char* sA = smem;            // 4 slots x 16KB
    char* sB = smem + 65536;    // 4 slots x 16KB

    // staging: thread tid stages LDS chunk q=tid (16B at tid*16, linear dest).
    // chunk q holds row r=q>>2, k-chunk (q&3)^((r>>1)&3)  [swizzle v2]
    const int r1  = tid >> 2;                               // 0..127
    const int cse = (((tid & 3) ^ ((tid >> 3) & 3)) << 3);  // source elem offset
    const unsigned short* ag0 = A + (row0 + r1      ) * (size_t)K + cse;
    const unsigned short* ag1 = A + (row0 + r1 + 128) * (size_t)K + cse;
    const unsigned short* bg0 = W + (col0 + r1      ) * (size_t)K + cse;
    const unsigned short* bg1 = W + (col0 + r1 + 128) * (size_t)K + cse;
    const int dst0 = tid * 16;
    const int dst1 = tid * 16 + 8192;

    auto stage = [&](int h, int s, int kt) {
        if (h == 0) {
            gl_lds16(ag0 + (size_t)kt * 32, sA + s * 16384 + dst0);
            gl_lds16(bg0 + (size_t)kt * 32, sB + s * 16384 + dst0);
        } else {
            gl_lds16(ag1 + (size_t)kt * 32, sA + s * 16384 + dst1);
            gl_lds16(bg1 + (size_t)kt * 32, sB + s * 16384 + dst1);
        }
    };

    // fragment reads: addr = row*64 + ((kchunk ^ ((row>>1)&3))*16); row bits[2:1]=lane bits[2:1]
    const int ln15 = lane & 15;
    const int xoff = (((lane >> 4) ^ ((lane >> 1) & 3)) << 4);   // bytes
    const int arow = wr * 128 + ln15;                            // + mi*16
    const int brow = wc * 64  + ln15;                            // + nf*16

    f32x4 acc[8][4] = {};

    // prologue: stage tiles 0,1,2 into slots 0,1,2
#pragma unroll
    for (int kt = 0; kt < 3; ++kt) {
        stage(0, kt, kt);
        stage(1, kt, kt);
    }
    WAITVM(8);      // tile 0 landed (tiles 1,2 in flight)
    SBAR();

    for (int k = 0; k < NT; ++k) {
        const int slot = k & 3;
        const char* cA = sA + slot * 16384;
        const char* cB = sB + slot * 16384;
        bf16x8 aF[8], bF[2];

        // ===== phase A (N-half 0) =====
#pragma unroll
        for (int mi = 0; mi < 8; ++mi)
            aF[mi] = *(const bf16x8*)(cA + (arow + mi * 16) * 64 + xoff);
        bF[0] = *(const bf16x8*)(cB + (brow +  0) * 64 + xoff);
        bF[1] = *(const bf16x8*)(cB + (brow + 16) * 64 + xoff);
        if (k < NT - 3) stage(0, (k + 3) & 3, k + 3);
        SBAR();
        WAITLG0();
        __builtin_amdgcn_s_setprio(1);
#pragma unroll
        for (int mi = 0; mi < 8; ++mi) {
            acc[mi][0] = __builtin_amdgcn_mfma_f32_16x16x32_bf16(aF[mi], bF[0], acc[mi][0], 0, 0, 0);
            acc[mi][1] = __builtin_amdgcn_mfma_f32_16x16x32_bf16(aF[mi], bF[1], acc[mi][1], 0, 0, 0);
        }
        __builtin_amdgcn_s_setprio(0);
        SBAR();

        // ===== phase B (N-half 1) =====
        bF[0] = *(const bf16x8*)(cB + (brow + 32) * 64 + xoff);
        bF[1] = *(const bf16x8*)(cB + (brow + 48) * 64 + xoff);
        if (k < NT - 3) stage(1, (k + 3) & 3, k + 3);
        if (k < NT - 3)       WAITVM(8);
        else if (k == NT - 3) WAITVM(4);
        else if (k == NT - 2) WAITVM(0);
        SBAR();
        WAITLG0();
        __builtin_amdgcn_s_setprio(1);
#pragma unroll
        for (int mi = 0; mi < 8; ++mi) {
            acc[mi][2] = __builtin_amdgcn_mfma_f32_16x16x32_bf16(aF[mi], bF[0], acc[mi][2], 0, 0, 0);
            acc[mi][3] = __builtin_amdgcn_mfma_f32_16x16x32_bf16(aF[mi], bF[1], acc[mi][3], 0, 0, 0);
        }
        __builtin_amdgcn_s_setprio(0);
        SBAR();
    }

    // epilogue: D layout col = lane&15, row = (lane>>4)*4 + reg
    const int lq = lane >> 4;
    if (EPI == 2) {
        float bv[4];
#pragma unroll
        for (int nf = 0; nf < 4; ++nf) bv[nf] = bias[col0 + wc * 64 + nf * 16 + ln15];
        const bool odd = (ln15 & 1);
#pragma unroll
        for (int nf = 0; nf < 4; ++nf) {
            const size_t col = col0 + wc * 64 + nf * 16 + ln15;
#pragma unroll
            for (int mi = 0; mi < 8; ++mi) {
#pragma unroll
                for (int r = 0; r < 4; ++r) {
                    const size_t row = row0 + wr * 128 + mi * 16 + lq * 4 + r;
                    float v = acc[mi][nf][r] + bv[nf];           // even lane: s, odd: t
                    float partner = __shfl_xor(v, 1, 64);
                    float zv = zin[row * N + col];
                    float res = odd ? (zv * __expf(partner) + v) : zv;
                    outf[row * N + col] = res;
                }
            }
        }
        // log_det partials: sum of s (even-lane v) per row
#pragma unroll
        for (int mi = 0; mi < 8; ++mi) {
#pragma unroll
            for (int r = 0; r < 4; ++r) {
                float sv = 0.f;
#pragma unroll
                for (int nf = 0; nf < 4; ++nf) sv += acc[mi][nf][r] + bv[nf];
                sv = odd ? 0.f : sv;
#pragma unroll
                for (int off = 1; off < 16; off <<= 1) sv += __shfl_xor(sv, off, 64);
                if (ln15 == 0) {
                    const size_t row = row0 + wr * 128 + mi * 16 + lq * 4 + r;
                    atomicAdd(&ldout[row], sv);
                }
            }
        }
    } else {
#pragma unroll
        for (int nf = 0; nf < 4; ++nf) {
            const size_t col = col0 + wc * 64 + nf * 16 + ln15;
            const float bv = bias[col];
#pragma unroll
            for (int mi = 0; mi < 8; ++mi) {
#pragma unroll
                for (int r = 0; r < 4; ++r) {
                    const size_t row = row0 + wr * 128 + mi * 16 + lq * 4 + r;
                    float v = acc[mi][nf][r] + bv;
                    if (EPI == 0) {
                        float g = 0.5f * v * (1.0f + erff(v * 0.70710678118654752f));
                        outb[row * N + col] = f2bf(g);
                    } else {
                        outf[row * N + col] = v;
                    }
                }
            }
        }
    }
}

__global__ void cvt_bf16(const float* __restrict__ in, unsigned short* __restrict__ out, int n4) {
    const int stride = gridDim.x * blockDim.x;
    for (int i = blockIdx.x * blockDim.x + threadIdx.x; i < n4; i += stride) {
        float4 v = ((const float4*)in)[i];
        us4 o{ f2bf(v.x), f2bf(v.y), f2bf(v.z), f2bf(v.w) };
        ((us4*)out)[i] = o;
    }
}

// W3 interleaved convert: out row c (0..1023) = W3 row (c&1 ? 512+(c>>1) : c>>1)
__global__ void cvt_w3i(const float* __restrict__ in, unsigned short* __restrict__ out, int n4) {
    const int stride = gridDim.x * blockDim.x;
    for (int i = blockIdx.x * blockDim.x + threadIdx.x; i < n4; i += stride) {
        int row = i >> 9;           // 512 float4 per 2048-col row
        int c4  = i & 511;
        int srcrow = (row & 1) ? 512 + (row >> 1) : (row >> 1);
        float4 v = ((const float4*)in)[srcrow * 512 + c4];
        us4 o{ f2bf(v.x), f2bf(v.y), f2bf(v.z), f2bf(v.w) };
        ((us4*)out)[i] = o;
    }
}

// zm[row][i] = bf16(z[row][2i])
__global__ void pack_even(const float* __restrict__ z, unsigned short* __restrict__ zm, int n4) {
    const int stride = gridDim.x * blockDim.x;
    for (int i = blockIdx.x * blockDim.x + threadIdx.x; i < n4; i += stride) {
        float4 v = ((const float4*)z)[i];
        us2 o{ f2bf(v.x), f2bf(v.z) };
        ((us2*)zm)[i] = o;
    }
}

// b3 interleave + ldout init (ldout[r] = ld[r]; atomics accumulate s-sums later)
__global__ void prep3(const float* __restrict__ b3, float* __restrict__ b3i,
                      const float* __restrict__ ld, float* __restrict__ ldout, int nrow) {
    const int stride = gridDim.x * blockDim.x;
    int i = blockIdx.x * blockDim.x + threadIdx.x;
    if (i < 1024) b3i[i] = b3[(i & 1) ? 512 + (i >> 1) : (i >> 1)];
    for (int r = i; r < nrow; r += stride) ldout[r] = ld[r];
}

extern "C" void kernel_launch(void* const* d_in, const int* in_sizes, int n_in,
                              void* d_out, int out_size, void* d_ws, size_t ws_size,
                              hipStream_t stream)
{
    const float* z  = (const float*)d_in[0];
    const float* ld = (const float*)d_in[1];
    const float* W1 = (const float*)d_in[2];
    const float* b1 = (const float*)d_in[3];
    const float* W2 = (const float*)d_in[4];
    const float* b2 = (const float*)d_in[5];
    const float* W3 = (const float*)d_in[6];
    const float* b3 = (const float*)d_in[7];

    float* out   = (float*)d_out;
    float* zout  = out;
    float* ldout = out + (size_t)16384 * 1024;

    char* w = (char*)d_ws;
    unsigned short* zm  = (unsigned short*)w; w += (size_t)16384 * 512 * 2;
    unsigned short* w1b = (unsigned short*)w; w += (size_t)2048 * 512 * 2;
    unsigned short* w2b = (unsigned short*)w; w += (size_t)2048 * 2048 * 2;
    unsigned short* w3i = (unsigned short*)w; w += (size_t)1024 * 2048 * 2;
    unsigned short* h1  = (unsigned short*)w; w += (size_t)16384 * 2048 * 2;
    unsigned short* h2  = (unsigned short*)w; w += (size_t)16384 * 2048 * 2;
    float*          b3i = (float*)w;          w += 1024 * 4;

    (void)hipFuncSetAttribute((const void*)&gemm256<0, 512,  2048>,
                              hipFuncAttributeMaxDynamicSharedMemorySize, 131072);
    (void)hipFuncSetAttribute((const void*)&gemm256<0, 2048, 2048>,
                              hipFuncAttributeMaxDynamicSharedMemorySize, 131072);
    (void)hipFuncSetAttribute((const void*)&gemm256<2, 2048, 1024>,
                              hipFuncAttributeMaxDynamicSharedMemorySize, 131072);

    cvt_bf16 <<<512,  256, 0, stream>>>(W1, w1b, 2048 * 512 / 4);
    cvt_bf16 <<<2048, 256, 0, stream>>>(W2, w2b, 2048 * 2048 / 4);
    cvt_w3i  <<<1024, 256, 0, stream>>>(W3, w3i, 1024 * 2048 / 4);
    pack_even<<<2048, 256, 0, stream>>>(z, zm, 16384 * 1024 / 4);
    prep3    <<<64,   256, 0, stream>>>(b3, b3i, ld, ldout, 16384);

    gemm256<0, 512,  2048><<<dim3(8, 64), 512, 131072, stream>>>(zm, w1b, b1, h1, nullptr, nullptr, nullptr);
    gemm256<0, 2048, 2048><<<dim3(8, 64), 512, 131072, stream>>>(h1, w2b, b2, h2, nullptr, nullptr, nullptr);
    gemm256<2, 2048, 1024><<<dim3(4, 64), 512, 131072, stream>>>(h2, w3i, b3i, nullptr, zout, z, ldout);
}

// Round 4
// 385.587 us; speedup vs baseline: 1.1301x; 1.0093x over previous
//
#include <hip/hip_runtime.h>
#include <hip/hip_bf16.h>
#include <cstdint>

typedef __bf16 bf16x8 __attribute__((ext_vector_type(8)));
typedef float  f32x4  __attribute__((ext_vector_type(4)));

struct alignas(4) us2 { unsigned short x, y; };
struct alignas(8) us4 { unsigned short x, y, z, w; };

__device__ __forceinline__ unsigned short f2bf(float f) {
    union { float f; unsigned u; } a; a.f = f;
    unsigned r = a.u + 0x7fffu + ((a.u >> 16) & 1u);   // round-to-nearest-even
    return (unsigned short)(r >> 16);
}

__device__ __forceinline__ void gl_lds16(const void* g, void* s) {
    __builtin_amdgcn_global_load_lds(
        (const __attribute__((address_space(1))) void*)g,
        (__attribute__((address_space(3))) void*)s, 16, 0, 0);
}

#define SBAR()    do { __builtin_amdgcn_sched_barrier(0); __builtin_amdgcn_s_barrier(); __builtin_amdgcn_sched_barrier(0); } while (0)
#define WAITLG0() do { asm volatile("s_waitcnt lgkmcnt(0)" ::: "memory"); __builtin_amdgcn_sched_barrier(0); } while (0)
#define WAITVM(N) do { asm volatile("s_waitcnt vmcnt(" #N ")" ::: "memory"); __builtin_amdgcn_sched_barrier(0); } while (0)

// C = A(MxK) @ W(NxK)^T, bf16 in, fp32 acc. 256x256 tile, BK=32, 8 waves (2Mx4N),
// quad-buffered LDS, stage k+3 while computing k, counted vmcnt(8).
// K-loop re-sliced into 4 thin phases per K-32 (8 per K-64 = m201 rate):
//   p0: read bF[0..3]+aF[0,1] -> 8 MFMA ; p1..p3: read 2 aF -> 8 MFMA.
// LDS swizzle v2 (0 bank conflicts): chunk-col ^= (row>>1)&3.
// EPI 0: outb = bf16(gelu_exact(acc+bias)) ; EPI 1: outf = acc+bias ;
// EPI 2: fused coupling (W interleaved s/t): even col -> s, odd -> t.
template<int EPI, int K, int N>
__global__ __launch_bounds__(512, 2)
void gemm256(const unsigned short* __restrict__ A,
             const unsigned short* __restrict__ W,
             const float* __restrict__ bias,
             unsigned short* __restrict__ outb,
             float* __restrict__ outf,
             const float* __restrict__ zin,
             float* __restrict__ ldout)
{
    extern __shared__ char smem[];
    constexpr int NT = K / 32;
    constexpr int GX = N / 256;

    const int tid  = threadIdx.x;
    const int lane = tid & 63;
    const int wv   = tid >> 6;           // 0..7
    const int wr   = wv >> 2, wc = wv & 3;

    // T1: bijective XCD swizzle (nwg divisible by 8 for all our shapes)
    const int bid = blockIdx.y * GX + blockIdx.x;
    const int nwg = GX * (int)gridDim.y;
    const int swz = (bid & 7) * (nwg >> 3) + (bid >> 3);
    const size_t row0 = (size_t)(swz / GX) * 256;
    const size_t col0 = (size_t)(swz % GX) * 256;

    char* sA = smem;            // 4 slots x 16KB
    char* sB = smem + 65536;    // 4 slots x 16KB

    // staging: thread tid stages LDS chunk q=tid (16B at tid*16, linear dest).
    // chunk q holds row r=q>>2, k-chunk (q&3)^((r>>1)&3)  [swizzle v2]
    const int r1  = tid >> 2;                               // 0..127
    const int cse = (((tid & 3) ^ ((tid >> 3) & 3)) << 3);  // source elem offset
    const unsigned short* ag0 = A + (row0 + r1      ) * (size_t)K + cse;
    const unsigned short* ag1 = A + (row0 + r1 + 128) * (size_t)K + cse;
    const unsigned short* bg0 = W + (col0 + r1      ) * (size_t)K + cse;
    const unsigned short* bg1 = W + (col0 + r1 + 128) * (size_t)K + cse;
    const int dst0 = tid * 16;
    const int dst1 = tid * 16 + 8192;

    auto stage = [&](int h, int s, int kt) {
        if (h == 0) {
            gl_lds16(ag0 + (size_t)kt * 32, sA + s * 16384 + dst0);
            gl_lds16(bg0 + (size_t)kt * 32, sB + s * 16384 + dst0);
        } else {
            gl_lds16(ag1 + (size_t)kt * 32, sA + s * 16384 + dst1);
            gl_lds16(bg1 + (size_t)kt * 32, sB + s * 16384 + dst1);
        }
    };

    // fragment reads: addr = row*64 + ((kchunk ^ ((row>>1)&3))*16); row bits[2:1]=lane bits[2:1]
    const int ln15 = lane & 15;
    const int xoff = (((lane >> 4) ^ ((lane >> 1) & 3)) << 4);   // bytes
    const int arow = wr * 128 + ln15;                            // + mi*16
    const int brow = wc * 64  + ln15;                            // + nf*16

    f32x4 acc[8][4] = {};

    // prologue: stage tiles 0,1,2 into slots 0,1,2
#pragma unroll
    for (int kt = 0; kt < 3; ++kt) {
        stage(0, kt, kt);
        stage(1, kt, kt);
    }
    WAITVM(8);      // tile 0 landed (tiles 1,2 in flight)
    SBAR();

    for (int k = 0; k < NT; ++k) {
        const int slot = k & 3;
        const char* cA = sA + slot * 16384;
        const char* cB = sB + slot * 16384;
        bf16x8 bF[4];

        // ===== phase 0: bF[0..3] + aF[0,1] ; MFMA mi 0,1 =====
        {
            bf16x8 a0 = *(const bf16x8*)(cA + (arow +  0) * 64 + xoff);
            bf16x8 a1 = *(const bf16x8*)(cA + (arow + 16) * 64 + xoff);
#pragma unroll
            for (int nf = 0; nf < 4; ++nf)
                bF[nf] = *(const bf16x8*)(cB + (brow + nf * 16) * 64 + xoff);
            SBAR();
            WAITLG0();
            __builtin_amdgcn_s_setprio(1);
#pragma unroll
            for (int nf = 0; nf < 4; ++nf) {
                acc[0][nf] = __builtin_amdgcn_mfma_f32_16x16x32_bf16(a0, bF[nf], acc[0][nf], 0, 0, 0);
                acc[1][nf] = __builtin_amdgcn_mfma_f32_16x16x32_bf16(a1, bF[nf], acc[1][nf], 0, 0, 0);
            }
            __builtin_amdgcn_s_setprio(0);
            SBAR();
        }

        // ===== phase 1: aF[2,3] ; stage h=0 ; MFMA mi 2,3 =====
        {
            bf16x8 a0 = *(const bf16x8*)(cA + (arow + 32) * 64 + xoff);
            bf16x8 a1 = *(const bf16x8*)(cA + (arow + 48) * 64 + xoff);
            if (k < NT - 3) stage(0, (k + 3) & 3, k + 3);
            SBAR();
            WAITLG0();
            __builtin_amdgcn_s_setprio(1);
#pragma unroll
            for (int nf = 0; nf < 4; ++nf) {
                acc[2][nf] = __builtin_amdgcn_mfma_f32_16x16x32_bf16(a0, bF[nf], acc[2][nf], 0, 0, 0);
                acc[3][nf] = __builtin_amdgcn_mfma_f32_16x16x32_bf16(a1, bF[nf], acc[3][nf], 0, 0, 0);
            }
            __builtin_amdgcn_s_setprio(0);
            SBAR();
        }

        // ===== phase 2: aF[4,5] ; MFMA mi 4,5 =====
        {
            bf16x8 a0 = *(const bf16x8*)(cA + (arow + 64) * 64 + xoff);
            bf16x8 a1 = *(const bf16x8*)(cA + (arow + 80) * 64 + xoff);
            SBAR();
            WAITLG0();
            __builtin_amdgcn_s_setprio(1);
#pragma unroll
            for (int nf = 0; nf < 4; ++nf) {
                acc[4][nf] = __builtin_amdgcn_mfma_f32_16x16x32_bf16(a0, bF[nf], acc[4][nf], 0, 0, 0);
                acc[5][nf] = __builtin_amdgcn_mfma_f32_16x16x32_bf16(a1, bF[nf], acc[5][nf], 0, 0, 0);
            }
            __builtin_amdgcn_s_setprio(0);
            SBAR();
        }

        // ===== phase 3: aF[6,7] ; stage h=1 ; vmcnt cert ; MFMA mi 6,7 =====
        {
            bf16x8 a0 = *(const bf16x8*)(cA + (arow +  96) * 64 + xoff);
            bf16x8 a1 = *(const bf16x8*)(cA + (arow + 112) * 64 + xoff);
            if (k < NT - 3) stage(1, (k + 3) & 3, k + 3);
            if (k < NT - 3)       WAITVM(8);
            else if (k == NT - 3) WAITVM(4);
            else if (k == NT - 2) WAITVM(0);
            SBAR();
            WAITLG0();
            __builtin_amdgcn_s_setprio(1);
#pragma unroll
            for (int nf = 0; nf < 4; ++nf) {
                acc[6][nf] = __builtin_amdgcn_mfma_f32_16x16x32_bf16(a0, bF[nf], acc[6][nf], 0, 0, 0);
                acc[7][nf] = __builtin_amdgcn_mfma_f32_16x16x32_bf16(a1, bF[nf], acc[7][nf], 0, 0, 0);
            }
            __builtin_amdgcn_s_setprio(0);
            SBAR();
        }
    }

    // epilogue: D layout col = lane&15, row = (lane>>4)*4 + reg
    const int lq = lane >> 4;
    if (EPI == 2) {
        float bv[4];
#pragma unroll
        for (int nf = 0; nf < 4; ++nf) bv[nf] = bias[col0 + wc * 64 + nf * 16 + ln15];
        const bool odd = (ln15 & 1);
#pragma unroll
        for (int nf = 0; nf < 4; ++nf) {
            const size_t col = col0 + wc * 64 + nf * 16 + ln15;
#pragma unroll
            for (int mi = 0; mi < 8; ++mi) {
#pragma unroll
                for (int r = 0; r < 4; ++r) {
                    const size_t row = row0 + wr * 128 + mi * 16 + lq * 4 + r;
                    float v = acc[mi][nf][r] + bv[nf];           // even lane: s, odd: t
                    float partner = __shfl_xor(v, 1, 64);
                    float zv = zin[row * N + col];
                    float res = odd ? (zv * __expf(partner) + v) : zv;
                    outf[row * N + col] = res;
                }
            }
        }
        // log_det partials: sum of s (even-lane v) per row
#pragma unroll
        for (int mi = 0; mi < 8; ++mi) {
#pragma unroll
            for (int r = 0; r < 4; ++r) {
                float sv = 0.f;
#pragma unroll
                for (int nf = 0; nf < 4; ++nf) sv += acc[mi][nf][r] + bv[nf];
                sv = odd ? 0.f : sv;
#pragma unroll
                for (int off = 1; off < 16; off <<= 1) sv += __shfl_xor(sv, off, 64);
                if (ln15 == 0) {
                    const size_t row = row0 + wr * 128 + mi * 16 + lq * 4 + r;
                    atomicAdd(&ldout[row], sv);
                }
            }
        }
    } else {
#pragma unroll
        for (int nf = 0; nf < 4; ++nf) {
            const size_t col = col0 + wc * 64 + nf * 16 + ln15;
            const float bv = bias[col];
#pragma unroll
            for (int mi = 0; mi < 8; ++mi) {
#pragma unroll
                for (int r = 0; r < 4; ++r) {
                    const size_t row = row0 + wr * 128 + mi * 16 + lq * 4 + r;
                    float v = acc[mi][nf][r] + bv;
                    if (EPI == 0) {
                        float g = 0.5f * v * (1.0f + erff(v * 0.70710678118654752f));
                        outb[row * N + col] = f2bf(g);
                    } else {
                        outf[row * N + col] = v;
                    }
                }
            }
        }
    }
}

__global__ void cvt_bf16(const float* __restrict__ in, unsigned short* __restrict__ out, int n4) {
    const int stride = gridDim.x * blockDim.x;
    for (int i = blockIdx.x * blockDim.x + threadIdx.x; i < n4; i += stride) {
        float4 v = ((const float4*)in)[i];
        us4 o{ f2bf(v.x), f2bf(v.y), f2bf(v.z), f2bf(v.w) };
        ((us4*)out)[i] = o;
    }
}

// W3 interleaved convert: out row c (0..1023) = W3 row (c&1 ? 512+(c>>1) : c>>1)
__global__ void cvt_w3i(const float* __restrict__ in, unsigned short* __restrict__ out, int n4) {
    const int stride = gridDim.x * blockDim.x;
    for (int i = blockIdx.x * blockDim.x + threadIdx.x; i < n4; i += stride) {
        int row = i >> 9;           // 512 float4 per 2048-col row
        int c4  = i & 511;
        int srcrow = (row & 1) ? 512 + (row >> 1) : (row >> 1);
        float4 v = ((const float4*)in)[srcrow * 512 + c4];
        us4 o{ f2bf(v.x), f2bf(v.y), f2bf(v.z), f2bf(v.w) };
        ((us4*)out)[i] = o;
    }
}

// zm[row][i] = bf16(z[row][2i])
__global__ void pack_even(const float* __restrict__ z, unsigned short* __restrict__ zm, int n4) {
    const int stride = gridDim.x * blockDim.x;
    for (int i = blockIdx.x * blockDim.x + threadIdx.x; i < n4; i += stride) {
        float4 v = ((const float4*)z)[i];
        us2 o{ f2bf(v.x), f2bf(v.z) };
        ((us2*)zm)[i] = o;
    }
}

// b3 interleave + ldout init
__global__ void prep3(const float* __restrict__ b3, float* __restrict__ b3i,
                      const float* __restrict__ ld, float* __restrict__ ldout, int nrow) {
    const int stride = gridDim.x * blockDim.x;
    int i = blockIdx.x * blockDim.x + threadIdx.x;
    if (i < 1024) b3i[i] = b3[(i & 1) ? 512 + (i >> 1) : (i >> 1)];
    for (int r = i; r < nrow; r += stride) ldout[r] = ld[r];
}

extern "C" void kernel_launch(void* const* d_in, const int* in_sizes, int n_in,
                              void* d_out, int out_size, void* d_ws, size_t ws_size,
                              hipStream_t stream)
{
    const float* z  = (const float*)d_in[0];
    const float* ld = (const float*)d_in[1];
    const float* W1 = (const float*)d_in[2];
    const float* b1 = (const float*)d_in[3];
    const float* W2 = (const float*)d_in[4];
    const float* b2 = (const float*)d_in[5];
    const float* W3 = (const float*)d_in[6];
    const float* b3 = (const float*)d_in[7];

    float* out   = (float*)d_out;
    float* zout  = out;
    float* ldout = out + (size_t)16384 * 1024;

    char* w = (char*)d_ws;
    unsigned short* zm  = (unsigned short*)w; w += (size_t)16384 * 512 * 2;
    unsigned short* w1b = (unsigned short*)w; w += (size_t)2048 * 512 * 2;
    unsigned short* w2b = (unsigned short*)w; w += (size_t)2048 * 2048 * 2;
    unsigned short* w3i = (unsigned short*)w; w += (size_t)1024 * 2048 * 2;
    unsigned short* h1  = (unsigned short*)w; w += (size_t)16384 * 2048 * 2;
    unsigned short* h2  = (unsigned short*)w; w += (size_t)16384 * 2048 * 2;
    float*          b3i = (float*)w;          w += 1024 * 4;

    (void)hipFuncSetAttribute((const void*)&gemm256<0, 512,  2048>,
                              hipFuncAttributeMaxDynamicSharedMemorySize, 131072);
    (void)hipFuncSetAttribute((const void*)&gemm256<0, 2048, 2048>,
                              hipFuncAttributeMaxDynamicSharedMemorySize, 131072);
    (void)hipFuncSetAttribute((const void*)&gemm256<2, 2048, 1024>,
                              hipFuncAttributeMaxDynamicSharedMemorySize, 131072);

    cvt_bf16 <<<512,  256, 0, stream>>>(W1, w1b, 2048 * 512 / 4);
    cvt_bf16 <<<2048, 256, 0, stream>>>(W2, w2b, 2048 * 2048 / 4);
    cvt_w3i  <<<1024, 256, 0, stream>>>(W3, w3i, 1024 * 2048 / 4);
    pack_even<<<2048, 256, 0, stream>>>(z, zm, 16384 * 1024 / 4);
    prep3    <<<64,   256, 0, stream>>>(b3, b3i, ld, ldout, 16384);

    gemm256<0, 512,  2048><<<dim3(8, 64), 512, 131072, stream>>>(zm, w1b, b1, h1, nullptr, nullptr, nullptr);
    gemm256<0, 2048, 2048><<<dim3(8, 64), 512, 131072, stream>>>(h1, w2b, b2, h2, nullptr, nullptr, nullptr);
    gemm256<2, 2048, 1024><<<dim3(4, 64), 512, 131072, stream>>>(h2, w3i, b3i, nullptr, zout, z, ldout);
}

// Round 5
// 364.869 us; speedup vs baseline: 1.1943x; 1.0568x over previous
//
#include <hip/hip_runtime.h>
#include <hip/hip_bf16.h>
#include <cstdint>

typedef __bf16 bf16x8 __attribute__((ext_vector_type(8)));
typedef float  f32x4  __attribute__((ext_vector_type(4)));

struct alignas(4) us2 { unsigned short x, y; };
struct alignas(8) us4 { unsigned short x, y, z, w; };

__device__ __forceinline__ unsigned short f2bf(float f) {
    union { float f; unsigned u; } a; a.f = f;
    unsigned r = a.u + 0x7fffu + ((a.u >> 16) & 1u);   // round-to-nearest-even
    return (unsigned short)(r >> 16);
}

__device__ __forceinline__ void gl_lds16(const void* g, void* s) {
    __builtin_amdgcn_global_load_lds(
        (const __attribute__((address_space(1))) void*)g,
        (__attribute__((address_space(3))) void*)s, 16, 0, 0);
}

#define SBAR()    do { __builtin_amdgcn_sched_barrier(0); __builtin_amdgcn_s_barrier(); __builtin_amdgcn_sched_barrier(0); } while (0)
#define WAITLG(N) do { asm volatile("s_waitcnt lgkmcnt(" #N ")" ::: "memory"); __builtin_amdgcn_sched_barrier(0); } while (0)
#define WAITVM(N) do { asm volatile("s_waitcnt vmcnt(" #N ")" ::: "memory"); __builtin_amdgcn_sched_barrier(0); } while (0)

// C = A(MxK) @ W(NxK)^T, bf16 in, fp32 acc. 256x256 tile, BK=32, 8 waves (2Mx4N),
// quad-buffered LDS (4 x 32KB slots), stage k+3 while computing k.
// AITER-style sync: ONE barrier + ONE counted vmcnt per K-tile (ladder 8/4/0);
// ds_reads pipelined one MFMA-step ahead, certified by counted lgkmcnt(2) (DS in-order).
// LDS swizzle v2 (0 bank conflicts measured): chunk-col ^= (row>>1)&3.
// EPI 0: outb = bf16(gelu_exact(acc+bias)) ; EPI 1: outf = acc+bias ;
// EPI 2: fused coupling (W interleaved s/t): even col -> s, odd -> t.
template<int EPI, int K, int N>
__global__ __launch_bounds__(512, 2)
void gemm256(const unsigned short* __restrict__ A,
             const unsigned short* __restrict__ W,
             const float* __restrict__ bias,
             unsigned short* __restrict__ outb,
             float* __restrict__ outf,
             const float* __restrict__ zin,
             float* __restrict__ ldout)
{
    extern __shared__ char smem[];
    constexpr int NT = K / 32;
    constexpr int GX = N / 256;

    const int tid  = threadIdx.x;
    const int lane = tid & 63;
    const int wv   = tid >> 6;           // 0..7
    const int wr   = wv >> 2, wc = wv & 3;

    // T1: bijective XCD swizzle (nwg divisible by 8 for all our shapes)
    const int bid = blockIdx.y * GX + blockIdx.x;
    const int nwg = GX * (int)gridDim.y;
    const int swz = (bid & 7) * (nwg >> 3) + (bid >> 3);
    const size_t row0 = (size_t)(swz / GX) * 256;
    const size_t col0 = (size_t)(swz % GX) * 256;

    char* sA = smem;            // 4 slots x 16KB
    char* sB = smem + 65536;    // 4 slots x 16KB

    // staging: thread tid stages LDS chunk q=tid (16B at tid*16, linear dest).
    // chunk q holds row r=q>>2, k-chunk (q&3)^((r>>1)&3)  [swizzle v2]
    const int r1  = tid >> 2;                               // 0..127
    const int cse = (((tid & 3) ^ ((tid >> 3) & 3)) << 3);  // source elem offset
    const unsigned short* ag0 = A + (row0 + r1      ) * (size_t)K + cse;
    const unsigned short* ag1 = A + (row0 + r1 + 128) * (size_t)K + cse;
    const unsigned short* bg0 = W + (col0 + r1      ) * (size_t)K + cse;
    const unsigned short* bg1 = W + (col0 + r1 + 128) * (size_t)K + cse;
    const int dst0 = tid * 16;
    const int dst1 = tid * 16 + 8192;

    auto stage = [&](int h, int s, int kt) {
        if (h == 0) {
            gl_lds16(ag0 + (size_t)kt * 32, sA + s * 16384 + dst0);
            gl_lds16(bg0 + (size_t)kt * 32, sB + s * 16384 + dst0);
        } else {
            gl_lds16(ag1 + (size_t)kt * 32, sA + s * 16384 + dst1);
            gl_lds16(bg1 + (size_t)kt * 32, sB + s * 16384 + dst1);
        }
    };

    // fragment reads: addr = row*64 + ((kchunk ^ ((row>>1)&3))*16); row bits[2:1]=lane bits[2:1]
    const int ln15 = lane & 15;
    const int xoff = (((lane >> 4) ^ ((lane >> 1) & 3)) << 4);   // bytes
    const int arow = wr * 128 + ln15;                            // + mi*16
    const int brow = wc * 64  + ln15;                            // + nf*16

    f32x4 acc[8][4] = {};

    // prologue: stage tiles 0,1,2 into slots 0,1,2 (12 loads in flight)
#pragma unroll
    for (int kt = 0; kt < 3; ++kt) {
        stage(0, kt, kt);
        stage(1, kt, kt);
    }

#define LDA(X)  (*(const bf16x8*)(cA + (arow + (X)) * 64 + xoff))
#define LDB(X)  (*(const bf16x8*)(cB + (brow + (X)) * 64 + xoff))
#define MM(mi, af) \
    acc[mi][0] = __builtin_amdgcn_mfma_f32_16x16x32_bf16(af, b0, acc[mi][0], 0, 0, 0); \
    acc[mi][1] = __builtin_amdgcn_mfma_f32_16x16x32_bf16(af, b1, acc[mi][1], 0, 0, 0); \
    acc[mi][2] = __builtin_amdgcn_mfma_f32_16x16x32_bf16(af, b2, acc[mi][2], 0, 0, 0); \
    acc[mi][3] = __builtin_amdgcn_mfma_f32_16x16x32_bf16(af, b3, acc[mi][3], 0, 0, 0);

    for (int k = 0; k < NT; ++k) {
        const char* cA = sA + (k & 3) * 16384;
        const char* cB = sB + (k & 3) * 16384;

        // ---- tile boundary: counted cert of slot k, then single barrier ----
        if (k <= NT - 3)      WAITVM(8);
        else if (k == NT - 2) WAITVM(4);
        else                  WAITVM(0);
        SBAR();

        // step-0 operands (6 reads) + step-1 operands (2 reads, stay in flight)
        bf16x8 a0 = LDA(0),  a1 = LDA(16);
        bf16x8 b0 = LDB(0),  b1 = LDB(16), b2 = LDB(32), b3 = LDB(48);
        bf16x8 a2 = LDA(32), a3 = LDA(48);
        if (k < NT - 3) stage(0, (k + 3) & 3, k + 3);
        WAITLG(2);                       // certify a0,a1,b0..b3 ; a2,a3 in flight
        __builtin_amdgcn_s_setprio(1);
        MM(0, a0) MM(1, a1)
        __builtin_amdgcn_s_setprio(0);

        bf16x8 a4 = LDA(64), a5 = LDA(80);
        WAITLG(2);                       // certify a2,a3 ; a4,a5 in flight
        __builtin_amdgcn_s_setprio(1);
        MM(2, a2) MM(3, a3)
        __builtin_amdgcn_s_setprio(0);

        bf16x8 a6 = LDA(96), a7 = LDA(112);
        if (k < NT - 3) stage(1, (k + 3) & 3, k + 3);
        WAITLG(2);                       // certify a4,a5 ; a6,a7 in flight
        __builtin_amdgcn_s_setprio(1);
        MM(4, a4) MM(5, a5)
        __builtin_amdgcn_s_setprio(0);

        WAITLG(0);                       // certify a6,a7
        __builtin_amdgcn_s_setprio(1);
        MM(6, a6) MM(7, a7)
        __builtin_amdgcn_s_setprio(0);
    }
#undef LDA
#undef LDB
#undef MM

    // epilogue: D layout col = lane&15, row = (lane>>4)*4 + reg
    const int lq = lane >> 4;
    if (EPI == 2) {
        float bv[4];
#pragma unroll
        for (int nf = 0; nf < 4; ++nf) bv[nf] = bias[col0 + wc * 64 + nf * 16 + ln15];
        const bool odd = (ln15 & 1);
#pragma unroll
        for (int nf = 0; nf < 4; ++nf) {
            const size_t col = col0 + wc * 64 + nf * 16 + ln15;
#pragma unroll
            for (int mi = 0; mi < 8; ++mi) {
#pragma unroll
                for (int r = 0; r < 4; ++r) {
                    const size_t row = row0 + wr * 128 + mi * 16 + lq * 4 + r;
                    float v = acc[mi][nf][r] + bv[nf];           // even lane: s, odd: t
                    float partner = __shfl_xor(v, 1, 64);
                    float zv = zin[row * N + col];
                    float res = odd ? (zv * __expf(partner) + v) : zv;
                    outf[row * N + col] = res;
                }
            }
        }
        // log_det partials: sum of s (even-lane v) per row
#pragma unroll
        for (int mi = 0; mi < 8; ++mi) {
#pragma unroll
            for (int r = 0; r < 4; ++r) {
                float sv = 0.f;
#pragma unroll
                for (int nf = 0; nf < 4; ++nf) sv += acc[mi][nf][r] + bv[nf];
                sv = odd ? 0.f : sv;
#pragma unroll
                for (int off = 1; off < 16; off <<= 1) sv += __shfl_xor(sv, off, 64);
                if (ln15 == 0) {
                    const size_t row = row0 + wr * 128 + mi * 16 + lq * 4 + r;
                    atomicAdd(&ldout[row], sv);
                }
            }
        }
    } else {
#pragma unroll
        for (int nf = 0; nf < 4; ++nf) {
            const size_t col = col0 + wc * 64 + nf * 16 + ln15;
            const float bv = bias[col];
#pragma unroll
            for (int mi = 0; mi < 8; ++mi) {
#pragma unroll
                for (int r = 0; r < 4; ++r) {
                    const size_t row = row0 + wr * 128 + mi * 16 + lq * 4 + r;
                    float v = acc[mi][nf][r] + bv;
                    if (EPI == 0) {
                        float g = 0.5f * v * (1.0f + erff(v * 0.70710678118654752f));
                        outb[row * N + col] = f2bf(g);
                    } else {
                        outf[row * N + col] = v;
                    }
                }
            }
        }
    }
}

__global__ void cvt_bf16(const float* __restrict__ in, unsigned short* __restrict__ out, int n4) {
    const int stride = gridDim.x * blockDim.x;
    for (int i = blockIdx.x * blockDim.x + threadIdx.x; i < n4; i += stride) {
        float4 v = ((const float4*)in)[i];
        us4 o{ f2bf(v.x), f2bf(v.y), f2bf(v.z), f2bf(v.w) };
        ((us4*)out)[i] = o;
    }
}

// W3 interleaved convert: out row c (0..1023) = W3 row (c&1 ? 512+(c>>1) : c>>1)
__global__ void cvt_w3i(const float* __restrict__ in, unsigned short* __restrict__ out, int n4) {
    const int stride = gridDim.x * blockDim.x;
    for (int i = blockIdx.x * blockDim.x + threadIdx.x; i < n4; i += stride) {
        int row = i >> 9;           // 512 float4 per 2048-col row
        int c4  = i & 511;
        int srcrow = (row & 1) ? 512 + (row >> 1) : (row >> 1);
        float4 v = ((const float4*)in)[srcrow * 512 + c4];
        us4 o{ f2bf(v.x), f2bf(v.y), f2bf(v.z), f2bf(v.w) };
        ((us4*)out)[i] = o;
    }
}

// zm[row][i] = bf16(z[row][2i])
__global__ void pack_even(const float* __restrict__ z, unsigned short* __restrict__ zm, int n4) {
    const int stride = gridDim.x * blockDim.x;
    for (int i = blockIdx.x * blockDim.x + threadIdx.x; i < n4; i += stride) {
        float4 v = ((const float4*)z)[i];
        us2 o{ f2bf(v.x), f2bf(v.z) };
        ((us2*)zm)[i] = o;
    }
}

// b3 interleave + ldout init
__global__ void prep3(const float* __restrict__ b3, float* __restrict__ b3i,
                      const float* __restrict__ ld, float* __restrict__ ldout, int nrow) {
    const int stride = gridDim.x * blockDim.x;
    int i = blockIdx.x * blockDim.x + threadIdx.x;
    if (i < 1024) b3i[i] = b3[(i & 1) ? 512 + (i >> 1) : (i >> 1)];
    for (int r = i; r < nrow; r += stride) ldout[r] = ld[r];
}

extern "C" void kernel_launch(void* const* d_in, const int* in_sizes, int n_in,
                              void* d_out, int out_size, void* d_ws, size_t ws_size,
                              hipStream_t stream)
{
    const float* z  = (const float*)d_in[0];
    const float* ld = (const float*)d_in[1];
    const float* W1 = (const float*)d_in[2];
    const float* b1 = (const float*)d_in[3];
    const float* W2 = (const float*)d_in[4];
    const float* b2 = (const float*)d_in[5];
    const float* W3 = (const float*)d_in[6];
    const float* b3 = (const float*)d_in[7];

    float* out   = (float*)d_out;
    float* zout  = out;
    float* ldout = out + (size_t)16384 * 1024;

    char* w = (char*)d_ws;
    unsigned short* zm  = (unsigned short*)w; w += (size_t)16384 * 512 * 2;
    unsigned short* w1b = (unsigned short*)w; w += (size_t)2048 * 512 * 2;
    unsigned short* w2b = (unsigned short*)w; w += (size_t)2048 * 2048 * 2;
    unsigned short* w3i = (unsigned short*)w; w += (size_t)1024 * 2048 * 2;
    unsigned short* h1  = (unsigned short*)w; w += (size_t)16384 * 2048 * 2;
    unsigned short* h2  = (unsigned short*)w; w += (size_t)16384 * 2048 * 2;
    float*          b3i = (float*)w;          w += 1024 * 4;

    (void)hipFuncSetAttribute((const void*)&gemm256<0, 512,  2048>,
                              hipFuncAttributeMaxDynamicSharedMemorySize, 131072);
    (void)hipFuncSetAttribute((const void*)&gemm256<0, 2048, 2048>,
                              hipFuncAttributeMaxDynamicSharedMemorySize, 131072);
    (void)hipFuncSetAttribute((const void*)&gemm256<2, 2048, 1024>,
                              hipFuncAttributeMaxDynamicSharedMemorySize, 131072);

    cvt_bf16 <<<512,  256, 0, stream>>>(W1, w1b, 2048 * 512 / 4);
    cvt_bf16 <<<2048, 256, 0, stream>>>(W2, w2b, 2048 * 2048 / 4);
    cvt_w3i  <<<1024, 256, 0, stream>>>(W3, w3i, 1024 * 2048 / 4);
    pack_even<<<2048, 256, 0, stream>>>(z, zm, 16384 * 1024 / 4);
    prep3    <<<64,   256, 0, stream>>>(b3, b3i, ld, ldout, 16384);

    gemm256<0, 512,  2048><<<dim3(8, 64), 512, 131072, stream>>>(zm, w1b, b1, h1, nullptr, nullptr, nullptr);
    gemm256<0, 2048, 2048><<<dim3(8, 64), 512, 131072, stream>>>(h1, w2b, b2, h2, nullptr, nullptr, nullptr);
    gemm256<2, 2048, 1024><<<dim3(4, 64), 512, 131072, stream>>>(h2, w3i, b3i, nullptr, zout, z, ldout);
}